// Round 1
// baseline (1104.396 us; speedup 1.0000x reference)
//
#include <hip/hip_runtime.h>
#include <math.h>

#define BDIM 4096
#define LDIM 1024
#define DDIM 256
#define EPSF 1e-6f

#define BM 64
#define BN 64
#define KT 16
#define LDSP 68   // 64 + 4 pad, keeps float4 alignment (multiple of 4)

// ---------------- norms: one block per row ----------------
__global__ __launch_bounds__(256) void norms_kernel(const float* __restrict__ x,
                                                    float* __restrict__ out, int L) {
    int row = blockIdx.x;
    const float* xr = x + (size_t)row * L;
    float s = 0.f;
    for (int t = threadIdx.x; t < L; t += 256) {
        float v = xr[t];
        s = fmaf(v, v, s);
    }
    #pragma unroll
    for (int off = 32; off > 0; off >>= 1) s += __shfl_down(s, off, 64);
    __shared__ float ws[4];
    int lane = threadIdx.x & 63, wid = threadIdx.x >> 6;
    if (lane == 0) ws[wid] = s;
    __syncthreads();
    if (threadIdx.x == 0) {
        out[row] = sqrtf(ws[0] + ws[1] + ws[2] + ws[3]);
    }
}

// ---------------- fused pair kernel ----------------
// Tile (i0..i0+64) x (j0..j0+64). Computes
//   c1 = cos(f_i, noise_j), c2 = cos(f_i, f_j), w = (1-cos(ref_i,ref_j))/2
// then neg_i += sum_{j != i} w*(exp(c1)+exp(c2));  pos_i = exp(c1_ii) on diagonal.
__global__ __launch_bounds__(256) void pair_kernel(
    const float* __restrict__ f, const float* __restrict__ noise,
    const float* __restrict__ ref,
    const float* __restrict__ nf, const float* __restrict__ nn,
    const float* __restrict__ nr,
    float* __restrict__ neg, float* __restrict__ pos)
{
    __shared__ float As[KT][LDSP];
    __shared__ float Bs1[KT][LDSP];
    __shared__ float Bs2[KT][LDSP];

    const int tid = threadIdx.x;
    const int tx = tid & 15, ty = tid >> 4;
    const int i0 = blockIdx.y * BM, j0 = blockIdx.x * BN;

    const int lr = tid >> 2;        // row 0..63 this thread stages
    const int lc = (tid & 3) * 4;   // col offset 0,4,8,12

    float acc1[16], acc2[16], accw[16];
    #pragma unroll
    for (int t = 0; t < 16; ++t) { acc1[t] = 0.f; acc2[t] = 0.f; accw[t] = 0.f; }

    // ---- phase 1: K = LDIM, A = f[i0], B1 = noise[j0], B2 = f[j0] ----
    for (int k0 = 0; k0 < LDIM; k0 += KT) {
        float4 av = *(const float4*)(f     + (size_t)(i0 + lr) * LDIM + k0 + lc);
        float4 b1 = *(const float4*)(noise + (size_t)(j0 + lr) * LDIM + k0 + lc);
        float4 b2 = *(const float4*)(f     + (size_t)(j0 + lr) * LDIM + k0 + lc);
        __syncthreads();
        As [lc+0][lr] = av.x; As [lc+1][lr] = av.y; As [lc+2][lr] = av.z; As [lc+3][lr] = av.w;
        Bs1[lc+0][lr] = b1.x; Bs1[lc+1][lr] = b1.y; Bs1[lc+2][lr] = b1.z; Bs1[lc+3][lr] = b1.w;
        Bs2[lc+0][lr] = b2.x; Bs2[lc+1][lr] = b2.y; Bs2[lc+2][lr] = b2.z; Bs2[lc+3][lr] = b2.w;
        __syncthreads();
        #pragma unroll
        for (int kk = 0; kk < KT; ++kk) {
            float4 a = *(const float4*)&As [kk][ty * 4];
            float4 b = *(const float4*)&Bs1[kk][tx * 4];
            float4 c = *(const float4*)&Bs2[kk][tx * 4];
            float av4[4] = {a.x, a.y, a.z, a.w};
            float bv4[4] = {b.x, b.y, b.z, b.w};
            float cv4[4] = {c.x, c.y, c.z, c.w};
            #pragma unroll
            for (int u = 0; u < 4; ++u)
                #pragma unroll
                for (int v = 0; v < 4; ++v) {
                    acc1[u*4+v] = fmaf(av4[u], bv4[v], acc1[u*4+v]);
                    acc2[u*4+v] = fmaf(av4[u], cv4[v], acc2[u*4+v]);
                }
        }
    }

    // ---- phase 2: K = DDIM, A = ref[i0], B1 = ref[j0] ----
    for (int k0 = 0; k0 < DDIM; k0 += KT) {
        float4 av = *(const float4*)(ref + (size_t)(i0 + lr) * DDIM + k0 + lc);
        float4 b1 = *(const float4*)(ref + (size_t)(j0 + lr) * DDIM + k0 + lc);
        __syncthreads();
        As [lc+0][lr] = av.x; As [lc+1][lr] = av.y; As [lc+2][lr] = av.z; As [lc+3][lr] = av.w;
        Bs1[lc+0][lr] = b1.x; Bs1[lc+1][lr] = b1.y; Bs1[lc+2][lr] = b1.z; Bs1[lc+3][lr] = b1.w;
        __syncthreads();
        #pragma unroll
        for (int kk = 0; kk < KT; ++kk) {
            float4 a = *(const float4*)&As [kk][ty * 4];
            float4 b = *(const float4*)&Bs1[kk][tx * 4];
            float av4[4] = {a.x, a.y, a.z, a.w};
            float bv4[4] = {b.x, b.y, b.z, b.w};
            #pragma unroll
            for (int u = 0; u < 4; ++u)
                #pragma unroll
                for (int v = 0; v < 4; ++v)
                    accw[u*4+v] = fmaf(av4[u], bv4[v], accw[u*4+v]);
        }
    }

    // ---- epilogue ----
    float nfi[4], nri[4], nnj[4], nfj[4], nrj[4];
    #pragma unroll
    for (int u = 0; u < 4; ++u) {
        nfi[u] = nf[i0 + ty*4 + u];
        nri[u] = nr[i0 + ty*4 + u];
    }
    #pragma unroll
    for (int v = 0; v < 4; ++v) {
        nnj[v] = nn[j0 + tx*4 + v];
        nfj[v] = nf[j0 + tx*4 + v];
        nrj[v] = nr[j0 + tx*4 + v];
    }

    float rowsum[4] = {0.f, 0.f, 0.f, 0.f};
    #pragma unroll
    for (int u = 0; u < 4; ++u) {
        int gi = i0 + ty*4 + u;
        #pragma unroll
        for (int v = 0; v < 4; ++v) {
            int gj = j0 + tx*4 + v;
            float c1 = acc1[u*4+v] / fmaxf(nfi[u] * nnj[v], EPSF);
            float c2 = acc2[u*4+v] / fmaxf(nfi[u] * nfj[v], EPSF);
            float w  = (1.0f - accw[u*4+v] / fmaxf(nri[u] * nrj[v], EPSF)) * 0.5f;
            float e1 = expf(c1);
            float e2 = expf(c2);
            if (gi == gj) {
                pos[gi] = e1;   // positive pair; both halves masked out of neg
            } else {
                rowsum[u] += w * (e1 + e2);
            }
        }
    }

    // reduce across tx (16 contiguous lanes per ty within a wave)
    #pragma unroll
    for (int off = 1; off < 16; off <<= 1) {
        #pragma unroll
        for (int u = 0; u < 4; ++u)
            rowsum[u] += __shfl_xor(rowsum[u], off, 64);
    }
    if (tx == 0) {
        #pragma unroll
        for (int u = 0; u < 4; ++u)
            atomicAdd(&neg[i0 + ty*4 + u], rowsum[u]);
    }
}

// ---------------- finalize ----------------
__global__ __launch_bounds__(256) void finalize_kernel(const float* __restrict__ neg,
                                                       const float* __restrict__ pos,
                                                       float* __restrict__ out) {
    float s = 0.f;
    for (int i = threadIdx.x; i < BDIM; i += 256) {
        s += logf(neg[i] + EPSF) - logf(pos[i]);
    }
    #pragma unroll
    for (int off = 32; off > 0; off >>= 1) s += __shfl_down(s, off, 64);
    __shared__ float ws[4];
    int lane = threadIdx.x & 63, wid = threadIdx.x >> 6;
    if (lane == 0) ws[wid] = s;
    __syncthreads();
    if (threadIdx.x == 0) {
        out[0] = (ws[0] + ws[1] + ws[2] + ws[3]) / (float)BDIM;
    }
}

extern "C" void kernel_launch(void* const* d_in, const int* in_sizes, int n_in,
                              void* d_out, int out_size, void* d_ws, size_t ws_size,
                              hipStream_t stream) {
    const float* f     = (const float*)d_in[0];
    const float* noise = (const float*)d_in[1];
    const float* ref   = (const float*)d_in[2];
    float* out = (float*)d_out;

    float* ws  = (float*)d_ws;
    float* nf  = ws;
    float* nn  = ws + BDIM;
    float* nr  = ws + 2 * BDIM;
    float* neg = ws + 3 * BDIM;
    float* pos = ws + 4 * BDIM;

    hipMemsetAsync(neg, 0, BDIM * sizeof(float), stream);

    norms_kernel<<<BDIM, 256, 0, stream>>>(f, nf, LDIM);
    norms_kernel<<<BDIM, 256, 0, stream>>>(noise, nn, LDIM);
    norms_kernel<<<BDIM, 256, 0, stream>>>(ref, nr, DDIM);

    dim3 grid(BDIM / BN, BDIM / BM);
    pair_kernel<<<grid, 256, 0, stream>>>(f, noise, ref, nf, nn, nr, neg, pos);

    finalize_kernel<<<1, 256, 0, stream>>>(neg, pos, out);
}

// Round 2
// 261.762 us; speedup vs baseline: 4.2191x; 4.2191x over previous
//
#include <hip/hip_runtime.h>
#include <hip/hip_bf16.h>
#include <math.h>

#define BDIM 4096
#define LDIM 1024
#define DDIM 256
#define EPSF 1e-6f
#define PITCH 72   // 64 + 8 bf16 pad: rows start 16B-aligned, frag reads ~conflict-free

typedef unsigned short ushort_t;
typedef __attribute__((ext_vector_type(8))) short short8;
typedef __attribute__((ext_vector_type(4))) float floatx4;

__device__ inline ushort_t f2bf(float x) {
    union { __hip_bfloat16 h; ushort_t u; } v;
    v.h = __float2bfloat16(x);
    return v.u;
}

// ---------------- fp32 -> bf16 converts ----------------
// cat = [noise; f] flattened: first 4096*1024 elems from noise, next from f.
__global__ __launch_bounds__(256) void convert_cat(const float* __restrict__ f,
                                                   const float* __restrict__ noise,
                                                   ushort_t* __restrict__ catb) {
    size_t base = ((size_t)blockIdx.x * 256 + threadIdx.x) * 4;
    const size_t half = (size_t)BDIM * LDIM;
    const float* src = (base < half) ? (noise + base) : (f + (base - half));
    float4 v = *(const float4*)src;
    ushort_t* o = catb + base;
    o[0] = f2bf(v.x); o[1] = f2bf(v.y); o[2] = f2bf(v.z); o[3] = f2bf(v.w);
}

__global__ __launch_bounds__(256) void convert_ref(const float* __restrict__ ref,
                                                   ushort_t* __restrict__ refb) {
    size_t base = ((size_t)blockIdx.x * 256 + threadIdx.x) * 4;
    float4 v = *(const float4*)(ref + base);
    ushort_t* o = refb + base;
    o[0] = f2bf(v.x); o[1] = f2bf(v.y); o[2] = f2bf(v.z); o[3] = f2bf(v.w);
}

// ---------------- norms: one block per row (fp32 inputs) ----------------
__global__ __launch_bounds__(256) void norms_kernel(const float* __restrict__ x,
                                                    float* __restrict__ out, int L) {
    int row = blockIdx.x;
    const float* xr = x + (size_t)row * L;
    float s = 0.f;
    for (int t = threadIdx.x; t < L; t += 256) {
        float v = xr[t];
        s = fmaf(v, v, s);
    }
    #pragma unroll
    for (int off = 32; off > 0; off >>= 1) s += __shfl_down(s, off, 64);
    __shared__ float ws[4];
    int lane = threadIdx.x & 63, wid = threadIdx.x >> 6;
    if (lane == 0) ws[wid] = s;
    __syncthreads();
    if (threadIdx.x == 0) out[row] = sqrtf(ws[0] + ws[1] + ws[2] + ws[3]);
}

// ---------------- fused MFMA pair kernel ----------------
// Output tile space: (i, j) in 4096 x 8192.
//   acc  = f_i . cat_j       (K=1024)
//   accw = ref_i . ref_{j mod B}  (K=256)
// epilogue: neg_i += sum_{j, (j&4095)!=i} w_ij * exp(cos_ij); pos_i = exp(cos_ii).
__global__ __launch_bounds__(256, 2) void pair_mfma(
    const ushort_t* __restrict__ catb,  // 8192 x 1024 bf16
    const ushort_t* __restrict__ refb,  // 4096 x 256 bf16
    const float* __restrict__ ncat,     // 8192: [||noise||; ||f||]
    const float* __restrict__ nr,       // 4096
    float* __restrict__ neg, float* __restrict__ pos)
{
    __shared__ __align__(16) ushort_t As[128 * PITCH];
    __shared__ __align__(16) ushort_t Bs[128 * PITCH];

    const int tid = threadIdx.x;
    const int wid = tid >> 6, ln = tid & 63;
    const int i0 = blockIdx.y * 128;
    const int j0 = blockIdx.x * 128;

    const int wm = (wid >> 1) * 64;     // wave row offset in tile
    const int wn = (wid & 1) * 64;      // wave col offset in tile
    const int quad = ln >> 4, l16 = ln & 15;

    // staging coords: thread stages 8 contiguous bf16 (16B) per round
    const int srow = tid >> 3;          // 0..31
    const int scol = (tid & 7) * 8;     // 0,8,..,56

    floatx4 acc[4][4], accw[4][4];
    #pragma unroll
    for (int a = 0; a < 4; ++a)
        #pragma unroll
        for (int b = 0; b < 4; ++b) {
            acc[a][b] = (floatx4){0.f, 0.f, 0.f, 0.f};
            accw[a][b] = (floatx4){0.f, 0.f, 0.f, 0.f};
        }

    // ---- phase W: K = 256, A = ref[i0..], B = ref[(j0 mod B)..] ----
    {
        const ushort_t* A2 = refb + (size_t)i0 * DDIM;
        const int jm0 = (j0 >= BDIM) ? (j0 - BDIM) : j0;
        const ushort_t* B2 = refb + (size_t)jm0 * DDIM;
        for (int k0 = 0; k0 < DDIM; k0 += 64) {
            __syncthreads();
            #pragma unroll
            for (int r = 0; r < 4; ++r) {
                int row = r * 32 + srow;
                short8 av = *(const short8*)(A2 + (size_t)row * DDIM + k0 + scol);
                short8 bv = *(const short8*)(B2 + (size_t)row * DDIM + k0 + scol);
                *(short8*)(As + row * PITCH + scol) = av;
                *(short8*)(Bs + row * PITCH + scol) = bv;
            }
            __syncthreads();
            #pragma unroll
            for (int kk = 0; kk < 2; ++kk) {
                short8 af[4], bf[4];
                #pragma unroll
                for (int mi = 0; mi < 4; ++mi)
                    af[mi] = *(const short8*)(As + (wm + mi * 16 + l16) * PITCH + kk * 32 + quad * 8);
                #pragma unroll
                for (int ni = 0; ni < 4; ++ni)
                    bf[ni] = *(const short8*)(Bs + (wn + ni * 16 + l16) * PITCH + kk * 32 + quad * 8);
                #pragma unroll
                for (int mi = 0; mi < 4; ++mi)
                    #pragma unroll
                    for (int ni = 0; ni < 4; ++ni)
                        accw[mi][ni] = __builtin_amdgcn_mfma_f32_16x16x32_bf16(
                            af[mi], bf[ni], accw[mi][ni], 0, 0, 0);
            }
        }
    }

    // ---- phase main: K = 1024, A = f rows (= cat rows 4096+i), B = cat rows ----
    {
        const ushort_t* A1 = catb + (size_t)(BDIM + i0) * LDIM;
        const ushort_t* B1 = catb + (size_t)j0 * LDIM;
        for (int k0 = 0; k0 < LDIM; k0 += 64) {
            __syncthreads();
            #pragma unroll
            for (int r = 0; r < 4; ++r) {
                int row = r * 32 + srow;
                short8 av = *(const short8*)(A1 + (size_t)row * LDIM + k0 + scol);
                short8 bv = *(const short8*)(B1 + (size_t)row * LDIM + k0 + scol);
                *(short8*)(As + row * PITCH + scol) = av;
                *(short8*)(Bs + row * PITCH + scol) = bv;
            }
            __syncthreads();
            #pragma unroll
            for (int kk = 0; kk < 2; ++kk) {
                short8 af[4], bf[4];
                #pragma unroll
                for (int mi = 0; mi < 4; ++mi)
                    af[mi] = *(const short8*)(As + (wm + mi * 16 + l16) * PITCH + kk * 32 + quad * 8);
                #pragma unroll
                for (int ni = 0; ni < 4; ++ni)
                    bf[ni] = *(const short8*)(Bs + (wn + ni * 16 + l16) * PITCH + kk * 32 + quad * 8);
                #pragma unroll
                for (int mi = 0; mi < 4; ++mi)
                    #pragma unroll
                    for (int ni = 0; ni < 4; ++ni)
                        acc[mi][ni] = __builtin_amdgcn_mfma_f32_16x16x32_bf16(
                            af[mi], bf[ni], acc[mi][ni], 0, 0, 0);
            }
        }
    }

    // ---- epilogue ----
    // C/D layout (verified m89/m91): col = lane&15, row = quad*4 + reg.
    float rowsum[4][4];  // [mi][reg]
    #pragma unroll
    for (int mi = 0; mi < 4; ++mi)
        #pragma unroll
        for (int r = 0; r < 4; ++r) rowsum[mi][r] = 0.f;

    // per-lane row norms (16 rows) and col norms (4 cols)
    float nfi[4][4], nri_[4][4];
    #pragma unroll
    for (int mi = 0; mi < 4; ++mi)
        #pragma unroll
        for (int r = 0; r < 4; ++r) {
            int gi = i0 + wm + mi * 16 + quad * 4 + r;
            nfi[mi][r] = ncat[BDIM + gi];   // ||f_i||
            nri_[mi][r] = nr[gi];
        }
    float nbj[4], nrj[4];
    int gj[4];
    #pragma unroll
    for (int ni = 0; ni < 4; ++ni) {
        gj[ni] = j0 + wn + ni * 16 + l16;
        nbj[ni] = ncat[gj[ni]];
        nrj[ni] = nr[gj[ni] & (BDIM - 1)];
    }

    #pragma unroll
    for (int mi = 0; mi < 4; ++mi)
        #pragma unroll
        for (int ni = 0; ni < 4; ++ni)
            #pragma unroll
            for (int r = 0; r < 4; ++r) {
                int gi = i0 + wm + mi * 16 + quad * 4 + r;
                float c = acc[mi][ni][r] / fmaxf(nfi[mi][r] * nbj[ni], EPSF);
                float w = (1.0f - accw[mi][ni][r] / fmaxf(nri_[mi][r] * nrj[ni], EPSF)) * 0.5f;
                float e = __expf(c);
                if ((gj[ni] & (BDIM - 1)) == gi) {
                    if (gj[ni] == gi) pos[gi] = e;   // positive pair (j < B half)
                } else {
                    rowsum[mi][r] += w * e;
                }
            }

    // reduce across the 16 lanes sharing the same rows (same quad)
    #pragma unroll
    for (int off = 1; off < 16; off <<= 1)
        #pragma unroll
        for (int mi = 0; mi < 4; ++mi)
            #pragma unroll
            for (int r = 0; r < 4; ++r)
                rowsum[mi][r] += __shfl_xor(rowsum[mi][r], off, 64);

    if (l16 == 0) {
        #pragma unroll
        for (int mi = 0; mi < 4; ++mi)
            #pragma unroll
            for (int r = 0; r < 4; ++r)
                atomicAdd(&neg[i0 + wm + mi * 16 + quad * 4 + r], rowsum[mi][r]);
    }
}

// ---------------- finalize ----------------
__global__ __launch_bounds__(256) void finalize_kernel(const float* __restrict__ neg,
                                                       const float* __restrict__ pos,
                                                       float* __restrict__ out) {
    float s = 0.f;
    for (int i = threadIdx.x; i < BDIM; i += 256)
        s += logf(neg[i] + EPSF) - logf(pos[i]);
    #pragma unroll
    for (int off = 32; off > 0; off >>= 1) s += __shfl_down(s, off, 64);
    __shared__ float ws[4];
    int lane = threadIdx.x & 63, wid = threadIdx.x >> 6;
    if (lane == 0) ws[wid] = s;
    __syncthreads();
    if (threadIdx.x == 0) out[0] = (ws[0] + ws[1] + ws[2] + ws[3]) / (float)BDIM;
}

extern "C" void kernel_launch(void* const* d_in, const int* in_sizes, int n_in,
                              void* d_out, int out_size, void* d_ws, size_t ws_size,
                              hipStream_t stream) {
    const float* f     = (const float*)d_in[0];
    const float* noise = (const float*)d_in[1];
    const float* ref   = (const float*)d_in[2];
    float* out = (float*)d_out;

    char* w = (char*)d_ws;
    ushort_t* catb = (ushort_t*)w;                               // 8192*1024*2 = 16 MB
    ushort_t* refb = (ushort_t*)(w + (size_t)16777216);          // 4096*256*2  = 2 MB
    float* ncat    = (float*)(w + (size_t)18874368);             // 8192 floats
    float* nr      = (float*)(w + (size_t)18907136);             // 4096 floats
    float* neg     = (float*)(w + (size_t)18923520);             // 4096 floats
    float* pos     = (float*)(w + (size_t)18939904);             // 4096 floats

    hipMemsetAsync(neg, 0, BDIM * sizeof(float), stream);

    convert_cat<<<2 * BDIM * LDIM / 1024, 256, 0, stream>>>(f, noise, catb);
    convert_ref<<<BDIM * DDIM / 1024, 256, 0, stream>>>(ref, refb);

    norms_kernel<<<BDIM, 256, 0, stream>>>(noise, ncat, LDIM);
    norms_kernel<<<BDIM, 256, 0, stream>>>(f, ncat + BDIM, LDIM);
    norms_kernel<<<BDIM, 256, 0, stream>>>(ref, nr, DDIM);

    dim3 grid(2 * BDIM / 128, BDIM / 128);
    pair_mfma<<<grid, 256, 0, stream>>>(catb, refb, ncat, nr, neg, pos);

    finalize_kernel<<<1, 256, 0, stream>>>(neg, pos, out);
}

// Round 3
// 254.615 us; speedup vs baseline: 4.3375x; 1.0281x over previous
//
#include <hip/hip_runtime.h>
#include <hip/hip_bf16.h>
#include <math.h>

#define BDIM 4096
#define LDIM 1024
#define DDIM 256
#define EPSF 1e-6f

typedef unsigned short ushort_t;
typedef __attribute__((ext_vector_type(8))) short short8;
typedef __attribute__((ext_vector_type(4))) float floatx4;

__device__ inline ushort_t f2bf(float x) {
    union { __hip_bfloat16 h; ushort_t u; } v;
    v.h = __float2bfloat16(x);
    return v.u;
}

// async global->LDS, 16 B per lane; lds dst must be wave-uniform base (+lane*16 implied)
__device__ inline void gl2lds16(const ushort_t* g, ushort_t* l) {
    __builtin_amdgcn_global_load_lds(
        (const __attribute__((address_space(1))) void*)g,
        (__attribute__((address_space(3))) void*)l,
        16, 0, 0);
}

// ---------------- fused prep: convert to bf16 + row norms, single pass ----------------
// blocks 0..8191: cat row b (b<4096: noise row b; else f row b-4096), L=1024
// blocks 8192..9215: 4 ref rows each (one wave per row), L=256
__global__ __launch_bounds__(256) void prep_kernel(
    const float* __restrict__ f, const float* __restrict__ noise,
    const float* __restrict__ ref,
    ushort_t* __restrict__ catb, ushort_t* __restrict__ refb,
    float* __restrict__ ncat, float* __restrict__ nr)
{
    const int b = blockIdx.x;
    const int tid = threadIdx.x;
    if (b < 2 * BDIM) {
        const float* src = (b < BDIM) ? (noise + (size_t)b * LDIM)
                                      : (f + (size_t)(b - BDIM) * LDIM);
        float4 v = *(const float4*)(src + tid * 4);
        ushort4 o = { f2bf(v.x), f2bf(v.y), f2bf(v.z), f2bf(v.w) };
        *(ushort4*)(catb + (size_t)b * LDIM + tid * 4) = o;
        float s = v.x * v.x + v.y * v.y + v.z * v.z + v.w * v.w;
        #pragma unroll
        for (int off = 32; off > 0; off >>= 1) s += __shfl_down(s, off, 64);
        __shared__ float ws[4];
        int lane = tid & 63, wv = tid >> 6;
        if (lane == 0) ws[wv] = s;
        __syncthreads();
        if (tid == 0) ncat[b] = sqrtf(ws[0] + ws[1] + ws[2] + ws[3]);
    } else {
        int r = (b - 2 * BDIM) * 4 + (tid >> 6);   // one wave per ref row
        int lane = tid & 63;
        float4 v = *(const float4*)(ref + (size_t)r * DDIM + lane * 4);
        ushort4 o = { f2bf(v.x), f2bf(v.y), f2bf(v.z), f2bf(v.w) };
        *(ushort4*)(refb + (size_t)r * DDIM + lane * 4) = o;
        float s = v.x * v.x + v.y * v.y + v.z * v.z + v.w * v.w;
        #pragma unroll
        for (int off = 32; off > 0; off >>= 1) s += __shfl_down(s, off, 64);
        if (lane == 0) nr[r] = sqrtf(s);
    }
}

// ---------------- fused MFMA pair kernel (m97-style staging) ----------------
// Output tile space (i, j) in 4096 x 8192:
//   acc  = f_i . cat_j            (K=1024)
//   accw = ref_i . ref_{j mod B}  (K=256)
__global__ __launch_bounds__(256, 2) void pair_mfma(
    const ushort_t* __restrict__ catb,  // 8192 x 1024 bf16
    const ushort_t* __restrict__ refb,  // 4096 x 256 bf16
    const float* __restrict__ ncat,     // 8192
    const float* __restrict__ nr,       // 4096
    float* __restrict__ neg, float* __restrict__ pos)
{
    // unpadded pitch-64 tiles: required by global_load_lds lane-ordered landing
    __shared__ __align__(16) ushort_t As[128 * 64];
    __shared__ __align__(16) ushort_t Bs[128 * 64];

    const int tid = threadIdx.x;
    const int wid = tid >> 6, ln = tid & 63;
    const int i0 = blockIdx.y * 128;
    const int j0 = blockIdx.x * 128;

    const int wm = (wid >> 1) * 64;     // wave row offset in output tile
    const int wn = (wid & 1) * 64;      // wave col offset
    const int quad = ln >> 4, l16 = ln & 15;

    // staging: wave stages rows [wid*32, wid*32+32) of each 128x64 tile.
    // per call: 8 rows; lane ln covers row +ln/8, elem col (ln&7)*8.
    const int wrow0 = wid * 32;
    const int lrow = ln >> 3;
    const int lcol = (ln & 7) * 8;

    floatx4 acc[4][4], accw[4][4];
    #pragma unroll
    for (int a = 0; a < 4; ++a)
        #pragma unroll
        for (int c = 0; c < 4; ++c) {
            acc[a][c] = (floatx4){0.f, 0.f, 0.f, 0.f};
            accw[a][c] = (floatx4){0.f, 0.f, 0.f, 0.f};
        }

    // ---- phase W: K = 256, A = ref[i0..], B = ref[(j0 mod B)..] ----
    {
        const ushort_t* A2 = refb + (size_t)i0 * DDIM;
        const int jm0 = (j0 >= BDIM) ? (j0 - BDIM) : j0;
        const ushort_t* B2 = refb + (size_t)jm0 * DDIM;
        for (int k0 = 0; k0 < DDIM; k0 += 64) {
            __syncthreads();
            #pragma unroll
            for (int t = 0; t < 4; ++t) {
                int row = wrow0 + t * 8;
                gl2lds16(A2 + (size_t)(row + lrow) * DDIM + k0 + lcol, As + row * 64);
                gl2lds16(B2 + (size_t)(row + lrow) * DDIM + k0 + lcol, Bs + row * 64);
            }
            __syncthreads();
            #pragma unroll
            for (int kk = 0; kk < 2; ++kk) {
                short8 af[4], bf[4];
                #pragma unroll
                for (int mi = 0; mi < 4; ++mi)
                    af[mi] = *(const short8*)(As + (wm + mi * 16 + l16) * 64 + kk * 32 + quad * 8);
                #pragma unroll
                for (int ni = 0; ni < 4; ++ni)
                    bf[ni] = *(const short8*)(Bs + (wn + ni * 16 + l16) * 64 + kk * 32 + quad * 8);
                #pragma unroll
                for (int mi = 0; mi < 4; ++mi)
                    #pragma unroll
                    for (int ni = 0; ni < 4; ++ni)
                        accw[mi][ni] = __builtin_amdgcn_mfma_f32_16x16x32_bf16(
                            af[mi], bf[ni], accw[mi][ni], 0, 0, 0);
            }
        }
    }

    // ---- phase main: K = 1024, A = cat rows 4096+i (= f), B = cat rows j ----
    {
        const ushort_t* A1 = catb + (size_t)(BDIM + i0) * LDIM;
        const ushort_t* B1 = catb + (size_t)j0 * LDIM;
        for (int k0 = 0; k0 < LDIM; k0 += 64) {
            __syncthreads();
            #pragma unroll
            for (int t = 0; t < 4; ++t) {
                int row = wrow0 + t * 8;
                gl2lds16(A1 + (size_t)(row + lrow) * LDIM + k0 + lcol, As + row * 64);
                gl2lds16(B1 + (size_t)(row + lrow) * LDIM + k0 + lcol, Bs + row * 64);
            }
            __syncthreads();
            #pragma unroll
            for (int kk = 0; kk < 2; ++kk) {
                short8 af[4], bf[4];
                #pragma unroll
                for (int mi = 0; mi < 4; ++mi)
                    af[mi] = *(const short8*)(As + (wm + mi * 16 + l16) * 64 + kk * 32 + quad * 8);
                #pragma unroll
                for (int ni = 0; ni < 4; ++ni)
                    bf[ni] = *(const short8*)(Bs + (wn + ni * 16 + l16) * 64 + kk * 32 + quad * 8);
                #pragma unroll
                for (int mi = 0; mi < 4; ++mi)
                    #pragma unroll
                    for (int ni = 0; ni < 4; ++ni)
                        acc[mi][ni] = __builtin_amdgcn_mfma_f32_16x16x32_bf16(
                            af[mi], bf[ni], acc[mi][ni], 0, 0, 0);
            }
        }
    }

    // ---- epilogue (C/D layout: col = lane&15, row = quad*4 + reg; m89/m91) ----
    float rowsum[4][4];
    #pragma unroll
    for (int mi = 0; mi < 4; ++mi)
        #pragma unroll
        for (int r = 0; r < 4; ++r) rowsum[mi][r] = 0.f;

    float nfi[4][4], nri_[4][4];
    #pragma unroll
    for (int mi = 0; mi < 4; ++mi)
        #pragma unroll
        for (int r = 0; r < 4; ++r) {
            int gi = i0 + wm + mi * 16 + quad * 4 + r;
            nfi[mi][r] = ncat[BDIM + gi];
            nri_[mi][r] = nr[gi];
        }
    float nbj[4], nrj[4];
    int gj[4];
    #pragma unroll
    for (int ni = 0; ni < 4; ++ni) {
        gj[ni] = j0 + wn + ni * 16 + l16;
        nbj[ni] = ncat[gj[ni]];
        nrj[ni] = nr[gj[ni] & (BDIM - 1)];
    }

    #pragma unroll
    for (int mi = 0; mi < 4; ++mi)
        #pragma unroll
        for (int ni = 0; ni < 4; ++ni)
            #pragma unroll
            for (int r = 0; r < 4; ++r) {
                int gi = i0 + wm + mi * 16 + quad * 4 + r;
                float c = acc[mi][ni][r] / fmaxf(nfi[mi][r] * nbj[ni], EPSF);
                float w = (1.0f - accw[mi][ni][r] / fmaxf(nri_[mi][r] * nrj[ni], EPSF)) * 0.5f;
                float e = __expf(c);
                if ((gj[ni] & (BDIM - 1)) == gi) {
                    if (gj[ni] == gi) pos[gi] = e;
                } else {
                    rowsum[mi][r] += w * e;
                }
            }

    #pragma unroll
    for (int off = 1; off < 16; off <<= 1)
        #pragma unroll
        for (int mi = 0; mi < 4; ++mi)
            #pragma unroll
            for (int r = 0; r < 4; ++r)
                rowsum[mi][r] += __shfl_xor(rowsum[mi][r], off, 64);

    if (l16 == 0) {
        #pragma unroll
        for (int mi = 0; mi < 4; ++mi)
            #pragma unroll
            for (int r = 0; r < 4; ++r)
                atomicAdd(&neg[i0 + wm + mi * 16 + quad * 4 + r], rowsum[mi][r]);
    }
}

// ---------------- finalize ----------------
__global__ __launch_bounds__(256) void finalize_kernel(const float* __restrict__ neg,
                                                       const float* __restrict__ pos,
                                                       float* __restrict__ out) {
    float s = 0.f;
    for (int i = threadIdx.x; i < BDIM; i += 256)
        s += logf(neg[i] + EPSF) - logf(pos[i]);
    #pragma unroll
    for (int off = 32; off > 0; off >>= 1) s += __shfl_down(s, off, 64);
    __shared__ float ws[4];
    int lane = threadIdx.x & 63, wid = threadIdx.x >> 6;
    if (lane == 0) ws[wid] = s;
    __syncthreads();
    if (threadIdx.x == 0) out[0] = (ws[0] + ws[1] + ws[2] + ws[3]) / (float)BDIM;
}

extern "C" void kernel_launch(void* const* d_in, const int* in_sizes, int n_in,
                              void* d_out, int out_size, void* d_ws, size_t ws_size,
                              hipStream_t stream) {
    const float* f     = (const float*)d_in[0];
    const float* noise = (const float*)d_in[1];
    const float* ref   = (const float*)d_in[2];
    float* out = (float*)d_out;

    char* w = (char*)d_ws;
    ushort_t* catb = (ushort_t*)w;                               // 16 MB
    ushort_t* refb = (ushort_t*)(w + (size_t)16777216);          // 2 MB
    float* ncat    = (float*)(w + (size_t)18874368);             // 8192 floats
    float* nr      = (float*)(w + (size_t)18907136);             // 4096 floats
    float* neg     = (float*)(w + (size_t)18923520);             // 4096 floats
    float* pos     = (float*)(w + (size_t)18939904);             // 4096 floats

    hipMemsetAsync(neg, 0, BDIM * sizeof(float), stream);

    prep_kernel<<<2 * BDIM + BDIM / 4, 256, 0, stream>>>(f, noise, ref, catb, refb, ncat, nr);

    dim3 grid(2 * BDIM / 128, BDIM / 128);
    pair_mfma<<<grid, 256, 0, stream>>>(catb, refb, ncat, nr, neg, pos);

    finalize_kernel<<<1, 256, 0, stream>>>(neg, pos, out);
}

// Round 4
// 234.233 us; speedup vs baseline: 4.7150x; 1.0870x over previous
//
#include <hip/hip_runtime.h>
#include <hip/hip_bf16.h>
#include <math.h>

#define BDIM 4096
#define LDIM 1024
#define DDIM 256
#define EPSF 1e-6f

typedef unsigned short ushort_t;
typedef __attribute__((ext_vector_type(8))) short short8;
typedef __attribute__((ext_vector_type(4))) float floatx4;
typedef __attribute__((ext_vector_type(2))) _Float16 half2v;

__device__ inline ushort_t f2bf(float x) {
    union { __hip_bfloat16 h; ushort_t u; } v;
    v.h = __float2bfloat16(x);
    return v.u;
}

__device__ inline void gl2lds16(const ushort_t* g, ushort_t* l) {
    __builtin_amdgcn_global_load_lds(
        (const __attribute__((address_space(1))) void*)g,
        (__attribute__((address_space(3))) void*)l,
        16, 0, 0);
}

// One GEMM phase: stage 128xklen A/B row-major bf16 tiles through LDS with
// XOR-swizzled 16B chunks (slot p of row r holds logical chunk p ^ (r&7)),
// accumulate 128x128 into acc (4 waves, 64x64 each, 16x16x32 MFMA).
template<int RL>
__device__ inline void gemm_phase(const ushort_t* __restrict__ A,
                                  const ushort_t* __restrict__ B,
                                  ushort_t* As, ushort_t* Bs,
                                  floatx4 (&acc)[4][4], int klen,
                                  int wid, int ln, int wm, int wn,
                                  int quad, int l16)
{
    const int lrow = ln >> 3;                       // row within 8-row issue
    const int scol = ((ln & 7) ^ (lrow & 7)) * 8;   // swizzled logical chunk
    for (int k0 = 0; k0 < klen; k0 += 64) {
        __syncthreads();
        #pragma unroll
        for (int t = 0; t < 4; ++t) {
            const int row0 = wid * 32 + t * 8;      // wave-uniform LDS base row
            gl2lds16(A + (size_t)(row0 + lrow) * RL + k0 + scol, As + row0 * 64);
            gl2lds16(B + (size_t)(row0 + lrow) * RL + k0 + scol, Bs + row0 * 64);
        }
        __syncthreads();
        #pragma unroll
        for (int kk = 0; kk < 2; ++kk) {
            const int sw = ((kk * 4 + quad) ^ (l16 & 7)) * 8;  // read-side swizzle
            short8 af[4], bf[4];
            #pragma unroll
            for (int mi = 0; mi < 4; ++mi)
                af[mi] = *(const short8*)(As + (wm + mi * 16 + l16) * 64 + sw);
            #pragma unroll
            for (int ni = 0; ni < 4; ++ni)
                bf[ni] = *(const short8*)(Bs + (wn + ni * 16 + l16) * 64 + sw);
            #pragma unroll
            for (int mi = 0; mi < 4; ++mi)
                #pragma unroll
                for (int ni = 0; ni < 4; ++ni)
                    acc[mi][ni] = __builtin_amdgcn_mfma_f32_16x16x32_bf16(
                        af[mi], bf[ni], acc[mi][ni], 0, 0, 0);
        }
    }
}

__device__ inline void reduce_atomic(float (&rowsum)[4][4], float* __restrict__ neg,
                                     int base_i, int quad, int l16)
{
    #pragma unroll
    for (int off = 1; off < 16; off <<= 1)
        #pragma unroll
        for (int mi = 0; mi < 4; ++mi)
            #pragma unroll
            for (int r = 0; r < 4; ++r)
                rowsum[mi][r] += __shfl_xor(rowsum[mi][r], off, 64);
    if (l16 == 0) {
        #pragma unroll
        for (int mi = 0; mi < 4; ++mi)
            #pragma unroll
            for (int r = 0; r < 4; ++r)
                atomicAdd(&neg[base_i + mi * 16 + quad * 4 + r], rowsum[mi][r]);
    }
}

// ---------------- prep: bf16 convert + inverse row norms, wave-per-row ----------------
// blocks 0..2047: 4 cat rows each (row<4096: noise, else f), L=1024
// blocks 2048..3071: 4 ref rows each, L=256
__global__ __launch_bounds__(256) void prep_kernel(
    const float* __restrict__ f, const float* __restrict__ noise,
    const float* __restrict__ ref,
    ushort_t* __restrict__ catb, ushort_t* __restrict__ refb,
    float* __restrict__ incat, float* __restrict__ inr)
{
    const int b = blockIdx.x;
    const int wv = threadIdx.x >> 6, lane = threadIdx.x & 63;
    if (b < 2048) {
        const int row = b * 4 + wv;  // cat row 0..8191
        const float* src = (row < BDIM) ? noise + (size_t)row * LDIM
                                        : f + (size_t)(row - BDIM) * LDIM;
        ushort_t* dst = catb + (size_t)row * LDIM;
        float s = 0.f;
        #pragma unroll
        for (int t = 0; t < 4; ++t) {
            float4 v = *(const float4*)(src + t * 256 + lane * 4);
            s += v.x * v.x + v.y * v.y + v.z * v.z + v.w * v.w;
            ushort4 o = { f2bf(v.x), f2bf(v.y), f2bf(v.z), f2bf(v.w) };
            *(ushort4*)(dst + t * 256 + lane * 4) = o;
        }
        #pragma unroll
        for (int off = 32; off > 0; off >>= 1) s += __shfl_down(s, off, 64);
        if (lane == 0) incat[row] = 1.0f / sqrtf(s);
    } else {
        const int row = (b - 2048) * 4 + wv;  // ref row 0..4095
        float4 v = *(const float4*)(ref + (size_t)row * DDIM + lane * 4);
        float s = v.x * v.x + v.y * v.y + v.z * v.z + v.w * v.w;
        ushort4 o = { f2bf(v.x), f2bf(v.y), f2bf(v.z), f2bf(v.w) };
        *(ushort4*)(refb + (size_t)row * DDIM + lane * 4) = o;
        #pragma unroll
        for (int off = 32; off > 0; off >>= 1) s += __shfl_down(s, off, 64);
        if (lane == 0) inr[row] = 1.0f / sqrtf(s);
    }
}

// ---------------- fused MFMA pair kernel, both j-halves per block ----------------
// Block (bi,bj): i0=bi*128, jm0=bj*128 (both < 4096).
//   W phase: accw = ref_i . ref_jm (K=256) -> fp16-packed weights (reused by BOTH halves)
//   main 1:  acc  = f_i . noise_jm (K=1024) -> epilogue (diag -> pos)
//   main 2:  acc  = f_i . f_jm     (K=1024) -> epilogue (diag skipped)
__global__ __launch_bounds__(256, 3) void pair_mfma(
    const ushort_t* __restrict__ catb,  // 8192 x 1024 bf16 [noise; f]
    const ushort_t* __restrict__ refb,  // 4096 x 256 bf16
    const float* __restrict__ incat,    // 8192 inverse norms
    const float* __restrict__ inr,      // 4096 inverse norms
    float* __restrict__ neg, float* __restrict__ pos)
{
    __shared__ __align__(16) ushort_t As[128 * 64];
    __shared__ __align__(16) ushort_t Bs[128 * 64];

    const int tid = threadIdx.x;
    const int wid = tid >> 6, ln = tid & 63;
    const int i0 = blockIdx.y * 128;
    const int jm0 = blockIdx.x * 128;
    const int wm = (wid >> 1) * 64, wn = (wid & 1) * 64;
    const int quad = ln >> 4, l16 = ln & 15;

    floatx4 acc[4][4];

    // ---- W phase ----
    #pragma unroll
    for (int a = 0; a < 4; ++a)
        #pragma unroll
        for (int c = 0; c < 4; ++c) acc[a][c] = (floatx4){0.f, 0.f, 0.f, 0.f};
    gemm_phase<DDIM>(refb + (size_t)i0 * DDIM, refb + (size_t)jm0 * DDIM,
                     As, Bs, acc, DDIM, wid, ln, wm, wn, quad, l16);

    half2v wpack[4][4][2];
    {
        float irow[4][4], icol[4];
        #pragma unroll
        for (int mi = 0; mi < 4; ++mi)
            #pragma unroll
            for (int r = 0; r < 4; ++r)
                irow[mi][r] = inr[i0 + wm + mi * 16 + quad * 4 + r];
        #pragma unroll
        for (int ni = 0; ni < 4; ++ni)
            icol[ni] = inr[jm0 + wn + ni * 16 + l16];
        #pragma unroll
        for (int mi = 0; mi < 4; ++mi)
            #pragma unroll
            for (int ni = 0; ni < 4; ++ni) {
                float w0 = (1.0f - acc[mi][ni][0] * irow[mi][0] * icol[ni]) * 0.5f;
                float w1 = (1.0f - acc[mi][ni][1] * irow[mi][1] * icol[ni]) * 0.5f;
                float w2 = (1.0f - acc[mi][ni][2] * irow[mi][2] * icol[ni]) * 0.5f;
                float w3 = (1.0f - acc[mi][ni][3] * irow[mi][3] * icol[ni]) * 0.5f;
                wpack[mi][ni][0] = (half2v){ (_Float16)w0, (_Float16)w1 };
                wpack[mi][ni][1] = (half2v){ (_Float16)w2, (_Float16)w3 };
            }
    }

    // ---- main 1: vs noise half (cols jm0..) ----
    #pragma unroll
    for (int a = 0; a < 4; ++a)
        #pragma unroll
        for (int c = 0; c < 4; ++c) acc[a][c] = (floatx4){0.f, 0.f, 0.f, 0.f};
    gemm_phase<LDIM>(catb + (size_t)(BDIM + i0) * LDIM, catb + (size_t)jm0 * LDIM,
                     As, Bs, acc, LDIM, wid, ln, wm, wn, quad, l16);
    {
        float ifi[4][4], inj[4];
        #pragma unroll
        for (int mi = 0; mi < 4; ++mi)
            #pragma unroll
            for (int r = 0; r < 4; ++r)
                ifi[mi][r] = incat[BDIM + i0 + wm + mi * 16 + quad * 4 + r];
        #pragma unroll
        for (int ni = 0; ni < 4; ++ni)
            inj[ni] = incat[jm0 + wn + ni * 16 + l16];
        float rowsum[4][4];
        #pragma unroll
        for (int mi = 0; mi < 4; ++mi)
            #pragma unroll
            for (int r = 0; r < 4; ++r) rowsum[mi][r] = 0.f;
        #pragma unroll
        for (int mi = 0; mi < 4; ++mi)
            #pragma unroll
            for (int ni = 0; ni < 4; ++ni)
                #pragma unroll
                for (int r = 0; r < 4; ++r) {
                    int gi = i0 + wm + mi * 16 + quad * 4 + r;
                    int gc = jm0 + wn + ni * 16 + l16;
                    float e = __expf(acc[mi][ni][r] * ifi[mi][r] * inj[ni]);
                    float w = (float)wpack[mi][ni][r >> 1][r & 1];
                    if (gc == gi) pos[gi] = e;
                    else rowsum[mi][r] += w * e;
                }
        reduce_atomic(rowsum, neg, i0 + wm, quad, l16);
    }

    // ---- main 2: vs f half (cols B + jm0..) ----
    #pragma unroll
    for (int a = 0; a < 4; ++a)
        #pragma unroll
        for (int c = 0; c < 4; ++c) acc[a][c] = (floatx4){0.f, 0.f, 0.f, 0.f};
    gemm_phase<LDIM>(catb + (size_t)(BDIM + i0) * LDIM, catb + (size_t)(BDIM + jm0) * LDIM,
                     As, Bs, acc, LDIM, wid, ln, wm, wn, quad, l16);
    {
        float ifi[4][4], inj[4];
        #pragma unroll
        for (int mi = 0; mi < 4; ++mi)
            #pragma unroll
            for (int r = 0; r < 4; ++r)
                ifi[mi][r] = incat[BDIM + i0 + wm + mi * 16 + quad * 4 + r];
        #pragma unroll
        for (int ni = 0; ni < 4; ++ni)
            inj[ni] = incat[BDIM + jm0 + wn + ni * 16 + l16];
        float rowsum[4][4];
        #pragma unroll
        for (int mi = 0; mi < 4; ++mi)
            #pragma unroll
            for (int r = 0; r < 4; ++r) rowsum[mi][r] = 0.f;
        #pragma unroll
        for (int mi = 0; mi < 4; ++mi)
            #pragma unroll
            for (int ni = 0; ni < 4; ++ni)
                #pragma unroll
                for (int r = 0; r < 4; ++r) {
                    int gi = i0 + wm + mi * 16 + quad * 4 + r;
                    int gc = jm0 + wn + ni * 16 + l16;
                    float e = __expf(acc[mi][ni][r] * ifi[mi][r] * inj[ni]);
                    float w = (float)wpack[mi][ni][r >> 1][r & 1];
                    if (gc != gi)  // j = i + B is the masked self pair
                        rowsum[mi][r] += w * e;
                }
        reduce_atomic(rowsum, neg, i0 + wm, quad, l16);
    }
}

// ---------------- finalize ----------------
__global__ __launch_bounds__(256) void finalize_kernel(const float* __restrict__ neg,
                                                       const float* __restrict__ pos,
                                                       float* __restrict__ out) {
    float s = 0.f;
    for (int i = threadIdx.x; i < BDIM; i += 256)
        s += logf(neg[i] + EPSF) - logf(pos[i]);
    #pragma unroll
    for (int off = 32; off > 0; off >>= 1) s += __shfl_down(s, off, 64);
    __shared__ float ws[4];
    int lane = threadIdx.x & 63, wid = threadIdx.x >> 6;
    if (lane == 0) ws[wid] = s;
    __syncthreads();
    if (threadIdx.x == 0) out[0] = (ws[0] + ws[1] + ws[2] + ws[3]) / (float)BDIM;
}

extern "C" void kernel_launch(void* const* d_in, const int* in_sizes, int n_in,
                              void* d_out, int out_size, void* d_ws, size_t ws_size,
                              hipStream_t stream) {
    const float* f     = (const float*)d_in[0];
    const float* noise = (const float*)d_in[1];
    const float* ref   = (const float*)d_in[2];
    float* out = (float*)d_out;

    char* w = (char*)d_ws;
    ushort_t* catb = (ushort_t*)w;                               // 16 MB
    ushort_t* refb = (ushort_t*)(w + (size_t)16777216);          // 2 MB
    float* incat   = (float*)(w + (size_t)18874368);             // 8192 floats
    float* inr     = (float*)(w + (size_t)18907136);             // 4096 floats
    float* neg     = (float*)(w + (size_t)18923520);             // 4096 floats
    float* pos     = (float*)(w + (size_t)18939904);             // 4096 floats

    hipMemsetAsync(neg, 0, BDIM * sizeof(float), stream);

    prep_kernel<<<3072, 256, 0, stream>>>(f, noise, ref, catb, refb, incat, inr);

    dim3 grid(BDIM / 128, BDIM / 128);
    pair_mfma<<<grid, 256, 0, stream>>>(catb, refb, incat, inr, neg, pos);

    finalize_kernel<<<1, 256, 0, stream>>>(neg, pos, out);
}

// Round 5
// 178.162 us; speedup vs baseline: 6.1988x; 1.3147x over previous
//
#include <hip/hip_runtime.h>
#include <hip/hip_bf16.h>
#include <math.h>

#define BDIM 4096
#define LDIM 1024
#define DDIM 256
#define EPSF 1e-6f

typedef unsigned short ushort_t;
typedef __attribute__((ext_vector_type(8))) short short8;
typedef __attribute__((ext_vector_type(4))) float floatx4;
typedef __attribute__((ext_vector_type(2))) _Float16 half2v;

__device__ inline ushort_t f2bf(float x) {
    union { __hip_bfloat16 h; ushort_t u; } v;
    v.h = __float2bfloat16(x);
    return v.u;
}

__device__ inline void gl2lds16(const ushort_t* g, ushort_t* l) {
    __builtin_amdgcn_global_load_lds(
        (const __attribute__((address_space(1))) void*)g,
        (__attribute__((address_space(3))) void*)l,
        16, 0, 0);
}

__device__ inline void reduce_atomic(float (&rowsum)[4][4], float* __restrict__ neg,
                                     int base_i, int quad, int l16)
{
    #pragma unroll
    for (int off = 1; off < 16; off <<= 1)
        #pragma unroll
        for (int mi = 0; mi < 4; ++mi)
            #pragma unroll
            for (int r = 0; r < 4; ++r)
                rowsum[mi][r] += __shfl_xor(rowsum[mi][r], off, 64);
    if (l16 == 0) {
        #pragma unroll
        for (int mi = 0; mi < 4; ++mi)
            #pragma unroll
            for (int r = 0; r < 4; ++r)
                atomicAdd(&neg[base_i + mi * 16 + quad * 4 + r], rowsum[mi][r]);
    }
}

// ---------------- prep: bf16 convert + inverse row norms + zero neg ----------------
// blocks 0..2047: 4 cat rows each (row<4096: noise, else f), L=1024
// blocks 2048..3071: 4 ref rows each (L=256) + zero 4 neg entries
__global__ __launch_bounds__(256) void prep_kernel(
    const float* __restrict__ f, const float* __restrict__ noise,
    const float* __restrict__ ref,
    ushort_t* __restrict__ catb, ushort_t* __restrict__ refb,
    float* __restrict__ incat, float* __restrict__ inr,
    float* __restrict__ neg)
{
    const int b = blockIdx.x;
    const int wv = threadIdx.x >> 6, lane = threadIdx.x & 63;
    if (b < 2048) {
        const int row = b * 4 + wv;  // cat row 0..8191
        const float* src = (row < BDIM) ? noise + (size_t)row * LDIM
                                        : f + (size_t)(row - BDIM) * LDIM;
        ushort_t* dst = catb + (size_t)row * LDIM;
        float s = 0.f;
        #pragma unroll
        for (int t = 0; t < 4; ++t) {
            float4 v = *(const float4*)(src + t * 256 + lane * 4);
            s += v.x * v.x + v.y * v.y + v.z * v.z + v.w * v.w;
            ushort4 o = { f2bf(v.x), f2bf(v.y), f2bf(v.z), f2bf(v.w) };
            *(ushort4*)(dst + t * 256 + lane * 4) = o;
        }
        #pragma unroll
        for (int off = 32; off > 0; off >>= 1) s += __shfl_down(s, off, 64);
        if (lane == 0) incat[row] = 1.0f / sqrtf(s);
    } else {
        const int row = (b - 2048) * 4 + wv;  // ref row 0..4095
        float4 v = *(const float4*)(ref + (size_t)row * DDIM + lane * 4);
        float s = v.x * v.x + v.y * v.y + v.z * v.z + v.w * v.w;
        ushort4 o = { f2bf(v.x), f2bf(v.y), f2bf(v.z), f2bf(v.w) };
        *(ushort4*)(refb + (size_t)row * DDIM + lane * 4) = o;
        #pragma unroll
        for (int off = 32; off > 0; off >>= 1) s += __shfl_down(s, off, 64);
        if (lane == 0) inr[row] = 1.0f / sqrtf(s);
        if (threadIdx.x == 0)
            *(float4*)(neg + (size_t)(b - 2048) * 4) = (float4){0.f, 0.f, 0.f, 0.f};
    }
}

// ---------------- fused MFMA pair kernel: W phase + interleaved dual GEMM ----------------
// Block (bi,bj): i0=bi*128, jm0=bj*128.
//   W phase: ref_i . ref_jm (K=256) -> fp16 weights (shared by both halves)
//   main:    ONE K-sweep staging As=f_i, Bs1=noise_jm, Bs2=f_jm; acc1, acc2 together
//   epilogue: neg_i += sum_j w * (e1 + e2) with diagonal handling; pos on diag of half 1.
__global__ __launch_bounds__(256, 2) void pair_mfma(
    const ushort_t* __restrict__ catb,  // 8192 x 1024 bf16 [noise; f]
    const ushort_t* __restrict__ refb,  // 4096 x 256 bf16
    const float* __restrict__ incat,    // 8192 inverse norms
    const float* __restrict__ inr,      // 4096 inverse norms
    float* __restrict__ neg, float* __restrict__ pos)
{
    __shared__ __align__(16) ushort_t As [128 * 64];
    __shared__ __align__(16) ushort_t Bs1[128 * 64];
    __shared__ __align__(16) ushort_t Bs2[128 * 64];

    const int tid = threadIdx.x;
    const int wid = tid >> 6, ln = tid & 63;
    const int i0 = blockIdx.y * 128;
    const int jm0 = blockIdx.x * 128;
    const int wm = (wid >> 1) * 64, wn = (wid & 1) * 64;
    const int quad = ln >> 4, l16 = ln & 15;

    // staging: lane covers row (wid*32 + t*8 + lrow), swizzled 16B chunk
    const int lrow = ln >> 3;
    const int scol = ((ln & 7) ^ lrow) * 8;

    // ---- W phase: K=256, As=ref[i0..], Bs1=ref[jm0..] ----
    half2v wpack[4][4][2];
    {
        floatx4 accw[4][4];
        #pragma unroll
        for (int a = 0; a < 4; ++a)
            #pragma unroll
            for (int c = 0; c < 4; ++c) accw[a][c] = (floatx4){0.f, 0.f, 0.f, 0.f};
        const ushort_t* A2 = refb + (size_t)i0 * DDIM;
        const ushort_t* B2 = refb + (size_t)jm0 * DDIM;
        for (int k0 = 0; k0 < DDIM; k0 += 64) {
            __syncthreads();
            #pragma unroll
            for (int t = 0; t < 4; ++t) {
                const int row0 = wid * 32 + t * 8;
                gl2lds16(A2 + (size_t)(row0 + lrow) * DDIM + k0 + scol, As  + row0 * 64);
                gl2lds16(B2 + (size_t)(row0 + lrow) * DDIM + k0 + scol, Bs1 + row0 * 64);
            }
            __syncthreads();
            #pragma unroll
            for (int kk = 0; kk < 2; ++kk) {
                const int sw = ((kk * 4 + quad) ^ (l16 & 7)) * 8;
                short8 af[4], bf[4];
                #pragma unroll
                for (int mi = 0; mi < 4; ++mi)
                    af[mi] = *(const short8*)(As + (wm + mi * 16 + l16) * 64 + sw);
                #pragma unroll
                for (int ni = 0; ni < 4; ++ni)
                    bf[ni] = *(const short8*)(Bs1 + (wn + ni * 16 + l16) * 64 + sw);
                #pragma unroll
                for (int mi = 0; mi < 4; ++mi)
                    #pragma unroll
                    for (int ni = 0; ni < 4; ++ni)
                        accw[mi][ni] = __builtin_amdgcn_mfma_f32_16x16x32_bf16(
                            af[mi], bf[ni], accw[mi][ni], 0, 0, 0);
            }
        }
        float irow[4], icol[4];
        #pragma unroll
        for (int ni = 0; ni < 4; ++ni)
            icol[ni] = inr[jm0 + wn + ni * 16 + l16];
        #pragma unroll
        for (int mi = 0; mi < 4; ++mi) {
            #pragma unroll
            for (int r = 0; r < 4; ++r)
                irow[r] = inr[i0 + wm + mi * 16 + quad * 4 + r];
            #pragma unroll
            for (int ni = 0; ni < 4; ++ni) {
                float w0 = (1.0f - accw[mi][ni][0] * irow[0] * icol[ni]) * 0.5f;
                float w1 = (1.0f - accw[mi][ni][1] * irow[1] * icol[ni]) * 0.5f;
                float w2 = (1.0f - accw[mi][ni][2] * irow[2] * icol[ni]) * 0.5f;
                float w3 = (1.0f - accw[mi][ni][3] * irow[3] * icol[ni]) * 0.5f;
                wpack[mi][ni][0] = (half2v){ (_Float16)w0, (_Float16)w1 };
                wpack[mi][ni][1] = (half2v){ (_Float16)w2, (_Float16)w3 };
            }
        }
    }

    // ---- main: single K-sweep, dual accumulate ----
    floatx4 acc1[4][4], acc2[4][4];
    #pragma unroll
    for (int a = 0; a < 4; ++a)
        #pragma unroll
        for (int c = 0; c < 4; ++c) {
            acc1[a][c] = (floatx4){0.f, 0.f, 0.f, 0.f};
            acc2[a][c] = (floatx4){0.f, 0.f, 0.f, 0.f};
        }
    {
        const ushort_t* Ag  = catb + (size_t)(BDIM + i0) * LDIM;
        const ushort_t* B1g = catb + (size_t)jm0 * LDIM;
        const ushort_t* B2g = catb + (size_t)(BDIM + jm0) * LDIM;
        for (int k0 = 0; k0 < LDIM; k0 += 64) {
            __syncthreads();
            #pragma unroll
            for (int t = 0; t < 4; ++t) {
                const int row0 = wid * 32 + t * 8;
                const size_t go = (size_t)(row0 + lrow) * LDIM + k0 + scol;
                gl2lds16(Ag  + go, As  + row0 * 64);
                gl2lds16(B1g + go, Bs1 + row0 * 64);
                gl2lds16(B2g + go, Bs2 + row0 * 64);
            }
            __syncthreads();
            #pragma unroll
            for (int kk = 0; kk < 2; ++kk) {
                const int sw = ((kk * 4 + quad) ^ (l16 & 7)) * 8;
                short8 af[4], bf1[4], bf2[4];
                #pragma unroll
                for (int mi = 0; mi < 4; ++mi)
                    af[mi] = *(const short8*)(As + (wm + mi * 16 + l16) * 64 + sw);
                #pragma unroll
                for (int ni = 0; ni < 4; ++ni) {
                    bf1[ni] = *(const short8*)(Bs1 + (wn + ni * 16 + l16) * 64 + sw);
                    bf2[ni] = *(const short8*)(Bs2 + (wn + ni * 16 + l16) * 64 + sw);
                }
                #pragma unroll
                for (int mi = 0; mi < 4; ++mi)
                    #pragma unroll
                    for (int ni = 0; ni < 4; ++ni) {
                        acc1[mi][ni] = __builtin_amdgcn_mfma_f32_16x16x32_bf16(
                            af[mi], bf1[ni], acc1[mi][ni], 0, 0, 0);
                        acc2[mi][ni] = __builtin_amdgcn_mfma_f32_16x16x32_bf16(
                            af[mi], bf2[ni], acc2[mi][ni], 0, 0, 0);
                    }
            }
        }
    }

    // ---- fused epilogue ----
    {
        float ifi[4][4], injn[4], injf[4];
        #pragma unroll
        for (int mi = 0; mi < 4; ++mi)
            #pragma unroll
            for (int r = 0; r < 4; ++r)
                ifi[mi][r] = incat[BDIM + i0 + wm + mi * 16 + quad * 4 + r];
        #pragma unroll
        for (int ni = 0; ni < 4; ++ni) {
            injn[ni] = incat[jm0 + wn + ni * 16 + l16];
            injf[ni] = incat[BDIM + jm0 + wn + ni * 16 + l16];
        }
        float rowsum[4][4];
        #pragma unroll
        for (int mi = 0; mi < 4; ++mi)
            #pragma unroll
            for (int r = 0; r < 4; ++r) rowsum[mi][r] = 0.f;
        #pragma unroll
        for (int mi = 0; mi < 4; ++mi)
            #pragma unroll
            for (int ni = 0; ni < 4; ++ni)
                #pragma unroll
                for (int r = 0; r < 4; ++r) {
                    int gi = i0 + wm + mi * 16 + quad * 4 + r;
                    int gc = jm0 + wn + ni * 16 + l16;
                    float e1 = __expf(acc1[mi][ni][r] * ifi[mi][r] * injn[ni]);
                    float e2 = __expf(acc2[mi][ni][r] * ifi[mi][r] * injf[ni]);
                    float w = (float)wpack[mi][ni][r >> 1][r & 1];
                    if (gc == gi) pos[gi] = e1;       // diag: pos, both pairs excluded
                    else rowsum[mi][r] += w * (e1 + e2);
                }
        reduce_atomic(rowsum, neg, i0 + wm, quad, l16);
    }
}

// ---------------- finalize ----------------
__global__ __launch_bounds__(256) void finalize_kernel(const float* __restrict__ neg,
                                                       const float* __restrict__ pos,
                                                       float* __restrict__ out) {
    float s = 0.f;
    for (int i = threadIdx.x; i < BDIM; i += 256)
        s += logf(neg[i] + EPSF) - logf(pos[i]);
    #pragma unroll
    for (int off = 32; off > 0; off >>= 1) s += __shfl_down(s, off, 64);
    __shared__ float ws[4];
    int lane = threadIdx.x & 63, wid = threadIdx.x >> 6;
    if (lane == 0) ws[wid] = s;
    __syncthreads();
    if (threadIdx.x == 0) out[0] = (ws[0] + ws[1] + ws[2] + ws[3]) / (float)BDIM;
}

extern "C" void kernel_launch(void* const* d_in, const int* in_sizes, int n_in,
                              void* d_out, int out_size, void* d_ws, size_t ws_size,
                              hipStream_t stream) {
    const float* f     = (const float*)d_in[0];
    const float* noise = (const float*)d_in[1];
    const float* ref   = (const float*)d_in[2];
    float* out = (float*)d_out;

    char* w = (char*)d_ws;
    ushort_t* catb = (ushort_t*)w;                               // 16 MB
    ushort_t* refb = (ushort_t*)(w + (size_t)16777216);          // 2 MB
    float* incat   = (float*)(w + (size_t)18874368);             // 8192 floats
    float* inr     = (float*)(w + (size_t)18907136);             // 4096 floats
    float* neg     = (float*)(w + (size_t)18923520);             // 4096 floats
    float* pos     = (float*)(w + (size_t)18939904);             // 4096 floats

    prep_kernel<<<3072, 256, 0, stream>>>(f, noise, ref, catb, refb, incat, inr, neg);

    dim3 grid(BDIM / 128, BDIM / 128);
    pair_mfma<<<grid, 256, 0, stream>>>(catb, refb, incat, inr, neg, pos);

    finalize_kernel<<<1, 256, 0, stream>>>(neg, pos, out);
}

// Round 6
// 165.965 us; speedup vs baseline: 6.6544x; 1.0735x over previous
//
#include <hip/hip_runtime.h>
#include <hip/hip_bf16.h>
#include <math.h>

#define BDIM 4096
#define LDIM 1024
#define DDIM 256
#define EPSF 1e-6f

typedef unsigned char uchar_t;
typedef __attribute__((ext_vector_type(4))) float floatx4;
typedef __attribute__((ext_vector_type(2))) _Float16 half2v;

__device__ inline void gl2lds16(const uchar_t* g, uchar_t* l) {
    __builtin_amdgcn_global_load_lds(
        (const __attribute__((address_space(1))) void*)g,
        (__attribute__((address_space(3))) void*)l,
        16, 0, 0);
}

// pack 4 fp32 -> 4 OCP e4m3 bytes (bytes [x,y,z,w] little-endian)
__device__ inline unsigned int pk4_fp8(float4 v) {
    unsigned int p = __builtin_amdgcn_cvt_pk_fp8_f32(v.x, v.y, 0u, false);
    p = __builtin_amdgcn_cvt_pk_fp8_f32(v.z, v.w, p, true);
    return p;
}

__device__ inline void reduce_atomic(float (&rowsum)[4][4], float* __restrict__ neg,
                                     int base_i, int quad, int l16)
{
    #pragma unroll
    for (int off = 1; off < 16; off <<= 1)
        #pragma unroll
        for (int mi = 0; mi < 4; ++mi)
            #pragma unroll
            for (int r = 0; r < 4; ++r)
                rowsum[mi][r] += __shfl_xor(rowsum[mi][r], off, 64);
    if (l16 == 0) {
        #pragma unroll
        for (int mi = 0; mi < 4; ++mi)
            #pragma unroll
            for (int r = 0; r < 4; ++r)
                atomicAdd(&neg[base_i + mi * 16 + quad * 4 + r], rowsum[mi][r]);
    }
}

// ---------------- prep: fp8 convert + inverse row norms + zero neg ----------------
// blocks 0..2047: 4 cat rows each (row<4096: noise, else f), L=1024
// blocks 2048..3071: 4 ref rows each (L=256) + zero 4 neg entries
__global__ __launch_bounds__(256) void prep_kernel(
    const float* __restrict__ f, const float* __restrict__ noise,
    const float* __restrict__ ref,
    uchar_t* __restrict__ catb, uchar_t* __restrict__ refb,
    float* __restrict__ incat, float* __restrict__ inr,
    float* __restrict__ neg)
{
    const int b = blockIdx.x;
    const int wv = threadIdx.x >> 6, lane = threadIdx.x & 63;
    if (b < 2048) {
        const int row = b * 4 + wv;  // cat row 0..8191
        const float* src = (row < BDIM) ? noise + (size_t)row * LDIM
                                        : f + (size_t)(row - BDIM) * LDIM;
        uchar_t* dst = catb + (size_t)row * LDIM;
        float s = 0.f;
        #pragma unroll
        for (int t = 0; t < 4; ++t) {
            float4 v = *(const float4*)(src + t * 256 + lane * 4);
            s += v.x * v.x + v.y * v.y + v.z * v.z + v.w * v.w;
            *(unsigned int*)(dst + t * 256 + lane * 4) = pk4_fp8(v);
        }
        #pragma unroll
        for (int off = 32; off > 0; off >>= 1) s += __shfl_down(s, off, 64);
        if (lane == 0) incat[row] = 1.0f / sqrtf(s);
    } else {
        const int row = (b - 2048) * 4 + wv;  // ref row 0..4095
        float4 v = *(const float4*)(ref + (size_t)row * DDIM + lane * 4);
        float s = v.x * v.x + v.y * v.y + v.z * v.z + v.w * v.w;
        *(unsigned int*)(refb + (size_t)row * DDIM + lane * 4) = pk4_fp8(v);
        #pragma unroll
        for (int off = 32; off > 0; off >>= 1) s += __shfl_down(s, off, 64);
        if (lane == 0) inr[row] = 1.0f / sqrtf(s);
        if (threadIdx.x == 0)
            *(float4*)(neg + (size_t)(b - 2048) * 4) = (float4){0.f, 0.f, 0.f, 0.f};
    }
}

// ---------------- fused fp8 MFMA pair kernel ----------------
// Block (bi,bj): i0=bi*128, jm0=bj*128.
//   W phase: ref_i . ref_jm (K=256) -> fp16 weights (shared by both halves)
//   main:    ONE K-sweep (K-step 128 fp8 = 128 B rows), As=f_i, Bs1=noise_jm, Bs2=f_jm
//   epilogue: neg_i += sum_j w * (e1 + e2); pos on diag of half 1.
// LDS geometry identical to round 5 (128 B rows, XOR-16B-chunk swizzle, 0 conflicts).
__global__ __launch_bounds__(256, 2) void pair_mfma(
    const uchar_t* __restrict__ catb,  // 8192 x 1024 fp8 [noise; f]
    const uchar_t* __restrict__ refb,  // 4096 x 256 fp8
    const float* __restrict__ incat,   // 8192 inverse norms
    const float* __restrict__ inr,     // 4096 inverse norms
    float* __restrict__ neg, float* __restrict__ pos)
{
    __shared__ __align__(16) uchar_t As [128 * 128];
    __shared__ __align__(16) uchar_t Bs1[128 * 128];
    __shared__ __align__(16) uchar_t Bs2[128 * 128];

    const int tid = threadIdx.x;
    const int wid = tid >> 6, ln = tid & 63;
    const int i0 = blockIdx.y * 128;
    const int jm0 = blockIdx.x * 128;
    const int wm = (wid >> 1) * 64, wn = (wid & 1) * 64;
    const int quad = ln >> 4, l16 = ln & 15;

    // staging: lane covers row (wid*32 + t*8 + lrow); 16B chunk (ln&7) ^ (row&7)
    const int lrow = ln >> 3;
    const int scol = ((ln & 7) ^ lrow) * 16;

    // read-side swizzled byte offsets within a 128 B row, per kk (K=32 each):
    // logical chunk = 2*kk + (quad>>1); physical = logical ^ (row&7) = ^ (l16&7)
    int co[4];
    #pragma unroll
    for (int kk = 0; kk < 4; ++kk)
        co[kk] = (((2 * kk + (quad >> 1)) ^ (l16 & 7)) * 16) + (quad & 1) * 8;

    // ---- W phase: K=256 (2 K-steps), As=ref[i0..], Bs1=ref[jm0..] ----
    half2v wpack[4][4][2];
    {
        floatx4 accw[4][4];
        #pragma unroll
        for (int a = 0; a < 4; ++a)
            #pragma unroll
            for (int c = 0; c < 4; ++c) accw[a][c] = (floatx4){0.f, 0.f, 0.f, 0.f};
        const uchar_t* A2 = refb + (size_t)i0 * DDIM;
        const uchar_t* B2 = refb + (size_t)jm0 * DDIM;
        for (int k0 = 0; k0 < DDIM; k0 += 128) {
            __syncthreads();
            #pragma unroll
            for (int t = 0; t < 4; ++t) {
                const int row0 = wid * 32 + t * 8;
                gl2lds16(A2 + (size_t)(row0 + lrow) * DDIM + k0 + scol, As  + row0 * 128);
                gl2lds16(B2 + (size_t)(row0 + lrow) * DDIM + k0 + scol, Bs1 + row0 * 128);
            }
            __syncthreads();
            #pragma unroll
            for (int kk = 0; kk < 4; ++kk) {
                long af[4], bf[4];
                #pragma unroll
                for (int mi = 0; mi < 4; ++mi)
                    af[mi] = *(const long*)(As + (wm + mi * 16 + l16) * 128 + co[kk]);
                #pragma unroll
                for (int ni = 0; ni < 4; ++ni)
                    bf[ni] = *(const long*)(Bs1 + (wn + ni * 16 + l16) * 128 + co[kk]);
                #pragma unroll
                for (int mi = 0; mi < 4; ++mi)
                    #pragma unroll
                    for (int ni = 0; ni < 4; ++ni)
                        accw[mi][ni] = __builtin_amdgcn_mfma_f32_16x16x32_fp8_fp8(
                            af[mi], bf[ni], accw[mi][ni], 0, 0, 0);
            }
        }
        float irow[4], icol[4];
        #pragma unroll
        for (int ni = 0; ni < 4; ++ni)
            icol[ni] = inr[jm0 + wn + ni * 16 + l16];
        #pragma unroll
        for (int mi = 0; mi < 4; ++mi) {
            #pragma unroll
            for (int r = 0; r < 4; ++r)
                irow[r] = inr[i0 + wm + mi * 16 + quad * 4 + r];
            #pragma unroll
            for (int ni = 0; ni < 4; ++ni) {
                float w0 = (1.0f - accw[mi][ni][0] * irow[0] * icol[ni]) * 0.5f;
                float w1 = (1.0f - accw[mi][ni][1] * irow[1] * icol[ni]) * 0.5f;
                float w2 = (1.0f - accw[mi][ni][2] * irow[2] * icol[ni]) * 0.5f;
                float w3 = (1.0f - accw[mi][ni][3] * irow[3] * icol[ni]) * 0.5f;
                wpack[mi][ni][0] = (half2v){ (_Float16)w0, (_Float16)w1 };
                wpack[mi][ni][1] = (half2v){ (_Float16)w2, (_Float16)w3 };
            }
        }
    }

    // ---- main: K=1024 (8 K-steps of 128), dual accumulate ----
    floatx4 acc1[4][4], acc2[4][4];
    #pragma unroll
    for (int a = 0; a < 4; ++a)
        #pragma unroll
        for (int c = 0; c < 4; ++c) {
            acc1[a][c] = (floatx4){0.f, 0.f, 0.f, 0.f};
            acc2[a][c] = (floatx4){0.f, 0.f, 0.f, 0.f};
        }
    {
        const uchar_t* Ag  = catb + (size_t)(BDIM + i0) * LDIM;
        const uchar_t* B1g = catb + (size_t)jm0 * LDIM;
        const uchar_t* B2g = catb + (size_t)(BDIM + jm0) * LDIM;
        for (int k0 = 0; k0 < LDIM; k0 += 128) {
            __syncthreads();
            #pragma unroll
            for (int t = 0; t < 4; ++t) {
                const int row0 = wid * 32 + t * 8;
                const size_t go = (size_t)(row0 + lrow) * LDIM + k0 + scol;
                gl2lds16(Ag  + go, As  + row0 * 128);
                gl2lds16(B1g + go, Bs1 + row0 * 128);
                gl2lds16(B2g + go, Bs2 + row0 * 128);
            }
            __syncthreads();
            #pragma unroll
            for (int kk = 0; kk < 4; ++kk) {
                long af[4], bf1[4], bf2[4];
                #pragma unroll
                for (int mi = 0; mi < 4; ++mi)
                    af[mi] = *(const long*)(As + (wm + mi * 16 + l16) * 128 + co[kk]);
                #pragma unroll
                for (int ni = 0; ni < 4; ++ni) {
                    bf1[ni] = *(const long*)(Bs1 + (wn + ni * 16 + l16) * 128 + co[kk]);
                    bf2[ni] = *(const long*)(Bs2 + (wn + ni * 16 + l16) * 128 + co[kk]);
                }
                #pragma unroll
                for (int mi = 0; mi < 4; ++mi)
                    #pragma unroll
                    for (int ni = 0; ni < 4; ++ni) {
                        acc1[mi][ni] = __builtin_amdgcn_mfma_f32_16x16x32_fp8_fp8(
                            af[mi], bf1[ni], acc1[mi][ni], 0, 0, 0);
                        acc2[mi][ni] = __builtin_amdgcn_mfma_f32_16x16x32_fp8_fp8(
                            af[mi], bf2[ni], acc2[mi][ni], 0, 0, 0);
                    }
            }
        }
    }

    // ---- fused epilogue ----
    {
        float ifi[4][4], injn[4], injf[4];
        #pragma unroll
        for (int mi = 0; mi < 4; ++mi)
            #pragma unroll
            for (int r = 0; r < 4; ++r)
                ifi[mi][r] = incat[BDIM + i0 + wm + mi * 16 + quad * 4 + r];
        #pragma unroll
        for (int ni = 0; ni < 4; ++ni) {
            injn[ni] = incat[jm0 + wn + ni * 16 + l16];
            injf[ni] = incat[BDIM + jm0 + wn + ni * 16 + l16];
        }
        float rowsum[4][4];
        #pragma unroll
        for (int mi = 0; mi < 4; ++mi)
            #pragma unroll
            for (int r = 0; r < 4; ++r) rowsum[mi][r] = 0.f;
        #pragma unroll
        for (int mi = 0; mi < 4; ++mi)
            #pragma unroll
            for (int ni = 0; ni < 4; ++ni)
                #pragma unroll
                for (int r = 0; r < 4; ++r) {
                    int gi = i0 + wm + mi * 16 + quad * 4 + r;
                    int gc = jm0 + wn + ni * 16 + l16;
                    float e1 = __expf(acc1[mi][ni][r] * ifi[mi][r] * injn[ni]);
                    float e2 = __expf(acc2[mi][ni][r] * ifi[mi][r] * injf[ni]);
                    float w = (float)wpack[mi][ni][r >> 1][r & 1];
                    if (gc == gi) pos[gi] = e1;       // diag: pos, both pairs excluded
                    else rowsum[mi][r] += w * (e1 + e2);
                }
        reduce_atomic(rowsum, neg, i0 + wm, quad, l16);
    }
}

// ---------------- finalize ----------------
__global__ __launch_bounds__(256) void finalize_kernel(const float* __restrict__ neg,
                                                       const float* __restrict__ pos,
                                                       float* __restrict__ out) {
    float s = 0.f;
    for (int i = threadIdx.x; i < BDIM; i += 256)
        s += logf(neg[i] + EPSF) - logf(pos[i]);
    #pragma unroll
    for (int off = 32; off > 0; off >>= 1) s += __shfl_down(s, off, 64);
    __shared__ float ws[4];
    int lane = threadIdx.x & 63, wid = threadIdx.x >> 6;
    if (lane == 0) ws[wid] = s;
    __syncthreads();
    if (threadIdx.x == 0) out[0] = (ws[0] + ws[1] + ws[2] + ws[3]) / (float)BDIM;
}

extern "C" void kernel_launch(void* const* d_in, const int* in_sizes, int n_in,
                              void* d_out, int out_size, void* d_ws, size_t ws_size,
                              hipStream_t stream) {
    const float* f     = (const float*)d_in[0];
    const float* noise = (const float*)d_in[1];
    const float* ref   = (const float*)d_in[2];
    float* out = (float*)d_out;

    char* w = (char*)d_ws;
    uchar_t* catb = (uchar_t*)w;                                 // 8192*1024 = 8 MB
    uchar_t* refb = (uchar_t*)(w + (size_t)8388608);             // 4096*256  = 1 MB
    float* incat  = (float*)(w + (size_t)9437184);               // 8192 floats
    float* inr    = (float*)(w + (size_t)9469952);               // 4096 floats
    float* neg    = (float*)(w + (size_t)9486336);               // 4096 floats
    float* pos    = (float*)(w + (size_t)9502720);               // 4096 floats

    prep_kernel<<<3072, 256, 0, stream>>>(f, noise, ref, catb, refb, incat, inr, neg);

    dim3 grid(BDIM / 128, BDIM / 128);
    pair_mfma<<<grid, 256, 0, stream>>>(catb, refb, incat, inr, neg, pos);

    finalize_kernel<<<1, 256, 0, stream>>>(neg, pos, out);
}

// Round 8
// 151.775 us; speedup vs baseline: 7.2765x; 1.0935x over previous
//
#include <hip/hip_runtime.h>
#include <hip/hip_bf16.h>
#include <math.h>

#define BDIM 4096
#define LDIM 1024
#define DDIM 256
#define EPSF 1e-6f

typedef unsigned char uchar_t;
typedef __attribute__((ext_vector_type(4))) float floatx4;
typedef __attribute__((ext_vector_type(2))) long longx2;

__device__ inline void gl2lds16(const uchar_t* g, uchar_t* l) {
    __builtin_amdgcn_global_load_lds(
        (const __attribute__((address_space(1))) void*)g,
        (__attribute__((address_space(3))) void*)l,
        16, 0, 0);
}

// pack 4 fp32 -> 4 OCP e4m3 bytes
__device__ inline unsigned int pk4_fp8(float a, float b, float c, float d) {
    unsigned int p = __builtin_amdgcn_cvt_pk_fp8_f32(a, b, 0u, false);
    p = __builtin_amdgcn_cvt_pk_fp8_f32(c, d, p, true);
    return p;
}
__device__ inline unsigned int pk4_fp8v(float4 v) { return pk4_fp8(v.x, v.y, v.z, v.w); }

__device__ inline void reduce_atomic(float (&rowsum)[4][4], float* __restrict__ neg,
                                     int base_i, int quad, int l16)
{
    #pragma unroll
    for (int off = 1; off < 16; off <<= 1)
        #pragma unroll
        for (int mi = 0; mi < 4; ++mi)
            #pragma unroll
            for (int r = 0; r < 4; ++r)
                rowsum[mi][r] += __shfl_xor(rowsum[mi][r], off, 64);
    if (l16 == 0) {
        #pragma unroll
        for (int mi = 0; mi < 4; ++mi)
            #pragma unroll
            for (int r = 0; r < 4; ++r)
                atomicAdd(&neg[base_i + mi * 16 + quad * 4 + r], rowsum[mi][r]);
    }
}

// ---------------- prep: fp8 convert + inverse row norms + zero neg ----------------
__global__ __launch_bounds__(256) void prep_kernel(
    const float* __restrict__ f, const float* __restrict__ noise,
    const float* __restrict__ ref,
    uchar_t* __restrict__ catb, uchar_t* __restrict__ refb,
    float* __restrict__ incat, float* __restrict__ inr,
    float* __restrict__ neg)
{
    const int b = blockIdx.x;
    const int wv = threadIdx.x >> 6, lane = threadIdx.x & 63;
    if (b < 2048) {
        const int row = b * 4 + wv;  // cat row 0..8191
        const float* src = (row < BDIM) ? noise + (size_t)row * LDIM
                                        : f + (size_t)(row - BDIM) * LDIM;
        uchar_t* dst = catb + (size_t)row * LDIM;
        float s = 0.f;
        #pragma unroll
        for (int t = 0; t < 4; ++t) {
            float4 v = *(const float4*)(src + t * 256 + lane * 4);
            s += v.x * v.x + v.y * v.y + v.z * v.z + v.w * v.w;
            *(unsigned int*)(dst + t * 256 + lane * 4) = pk4_fp8v(v);
        }
        #pragma unroll
        for (int off = 32; off > 0; off >>= 1) s += __shfl_down(s, off, 64);
        if (lane == 0) incat[row] = 1.0f / sqrtf(s);
    } else {
        const int row = (b - 2048) * 4 + wv;  // ref row 0..4095
        float4 v = *(const float4*)(ref + (size_t)row * DDIM + lane * 4);
        float s = v.x * v.x + v.y * v.y + v.z * v.z + v.w * v.w;
        *(unsigned int*)(refb + (size_t)row * DDIM + lane * 4) = pk4_fp8v(v);
        #pragma unroll
        for (int off = 32; off > 0; off >>= 1) s += __shfl_down(s, off, 64);
        if (lane == 0) inr[row] = 1.0f / sqrtf(s);
        if (threadIdx.x == 0)
            *(float4*)(neg + (size_t)(b - 2048) * 4) = (float4){0.f, 0.f, 0.f, 0.f};
    }
}

// ---------------- fused fp8 MFMA pair kernel ----------------
// K-order trick: dot products are K-permutation invariant and A/B MFMA operands
// pair bytes by (quad, j) identically, so both sides read the SAME 16B chunks
// (c = g*4+quad, XOR-swizzled) and feed lo/hi 8B to two MFMA K-steps.
// acc1 doubles as the W-phase accumulator; weights live in lane-private fp8 LDS.
__global__ __launch_bounds__(256, 2) void pair_mfma(
    const uchar_t* __restrict__ catb,  // 8192 x 1024 fp8 [noise; f]
    const uchar_t* __restrict__ refb,  // 4096 x 256 fp8
    const float* __restrict__ incat,   // 8192 inverse norms
    const float* __restrict__ inr,     // 4096 inverse norms
    float* __restrict__ neg, float* __restrict__ pos)
{
    __shared__ __align__(16) uchar_t As [128 * 128];
    __shared__ __align__(16) uchar_t Bs1[128 * 128];
    __shared__ __align__(16) uchar_t Bs2[128 * 128];
    __shared__ __align__(16) uchar_t Wl [256 * 80];  // stride 80: b128 conflict-free

    const int tid = threadIdx.x;
    const int wid = tid >> 6, ln = tid & 63;
    const int i0 = blockIdx.y * 128, jm0 = blockIdx.x * 128;
    const int wm = (wid >> 1) * 64, wn = (wid & 1) * 64;
    const int quad = ln >> 4, l16 = ln & 15;
    const int lrow = ln >> 3;
    const int scol = ((ln & 7) ^ lrow) * 16;  // staging: LDS slot s holds chunk s^(row&7)

    floatx4 acc1[4][4], acc2[4][4];

    // ================= W phase: ref_i . ref_jm (K=256), acc1 as accumulator =================
    #pragma unroll
    for (int a = 0; a < 4; ++a)
        #pragma unroll
        for (int c = 0; c < 4; ++c) acc1[a][c] = (floatx4){0.f, 0.f, 0.f, 0.f};
    {
        const uchar_t* A2 = refb + (size_t)i0 * DDIM;
        const uchar_t* B2 = refb + (size_t)jm0 * DDIM;
        for (int k0 = 0; k0 < DDIM; k0 += 128) {
            __syncthreads();
            #pragma unroll
            for (int t = 0; t < 4; ++t) {
                const int row0 = wid * 32 + t * 8;
                gl2lds16(A2 + (size_t)(row0 + lrow) * DDIM + k0 + scol, As  + row0 * 128);
                gl2lds16(B2 + (size_t)(row0 + lrow) * DDIM + k0 + scol, Bs1 + row0 * 128);
            }
            __syncthreads();
            #pragma unroll
            for (int g = 0; g < 2; ++g) {
                const int sw = ((g * 4 + quad) ^ (l16 & 7)) * 16;
                longx2 af[4], bf[4];
                #pragma unroll
                for (int mi = 0; mi < 4; ++mi)
                    af[mi] = *(const longx2*)(As + (wm + mi * 16 + l16) * 128 + sw);
                #pragma unroll
                for (int ni = 0; ni < 4; ++ni)
                    bf[ni] = *(const longx2*)(Bs1 + (wn + ni * 16 + l16) * 128 + sw);
                #pragma unroll
                for (int h = 0; h < 2; ++h)
                    #pragma unroll
                    for (int mi = 0; mi < 4; ++mi)
                        #pragma unroll
                        for (int ni = 0; ni < 4; ++ni)
                            acc1[mi][ni] = __builtin_amdgcn_mfma_f32_16x16x32_fp8_fp8(
                                af[mi][h], bf[ni][h], acc1[mi][ni], 0, 0, 0);
            }
        }
        // weights -> fp8 in lane-private LDS (read back by the SAME lane: no barrier needed)
        uchar_t* wl = Wl + tid * 80;
        float icol[4];
        #pragma unroll
        for (int ni = 0; ni < 4; ++ni)
            icol[ni] = inr[jm0 + wn + ni * 16 + l16];
        #pragma unroll
        for (int mi = 0; mi < 4; ++mi) {
            float ir0 = inr[i0 + wm + mi * 16 + quad * 4 + 0];
            float ir1 = inr[i0 + wm + mi * 16 + quad * 4 + 1];
            float ir2 = inr[i0 + wm + mi * 16 + quad * 4 + 2];
            float ir3 = inr[i0 + wm + mi * 16 + quad * 4 + 3];
            unsigned int wq[4];
            #pragma unroll
            for (int ni = 0; ni < 4; ++ni)
                wq[ni] = pk4_fp8((1.0f - acc1[mi][ni][0] * ir0 * icol[ni]) * 0.5f,
                                 (1.0f - acc1[mi][ni][1] * ir1 * icol[ni]) * 0.5f,
                                 (1.0f - acc1[mi][ni][2] * ir2 * icol[ni]) * 0.5f,
                                 (1.0f - acc1[mi][ni][3] * ir3 * icol[ni]) * 0.5f);
            *(uint4*)(wl + mi * 16) = (uint4){wq[0], wq[1], wq[2], wq[3]};
        }
    }

    // ================= main: f_i . [noise_jm | f_jm] (K=1024), dual accumulate =================
    #pragma unroll
    for (int a = 0; a < 4; ++a)
        #pragma unroll
        for (int c = 0; c < 4; ++c) {
            acc1[a][c] = (floatx4){0.f, 0.f, 0.f, 0.f};
            acc2[a][c] = (floatx4){0.f, 0.f, 0.f, 0.f};
        }
    {
        const uchar_t* Ag  = catb + (size_t)(BDIM + i0) * LDIM;
        const uchar_t* B1g = catb + (size_t)jm0 * LDIM;
        const uchar_t* B2g = catb + (size_t)(BDIM + jm0) * LDIM;
        for (int k0 = 0; k0 < LDIM; k0 += 128) {
            __syncthreads();
            #pragma unroll
            for (int t = 0; t < 4; ++t) {
                const int row0 = wid * 32 + t * 8;
                const size_t go = (size_t)(row0 + lrow) * LDIM + k0 + scol;
                gl2lds16(Ag  + go, As  + row0 * 128);
                gl2lds16(B1g + go, Bs1 + row0 * 128);
                gl2lds16(B2g + go, Bs2 + row0 * 128);
            }
            __syncthreads();
            #pragma unroll
            for (int g = 0; g < 2; ++g) {
                const int sw = ((g * 4 + quad) ^ (l16 & 7)) * 16;
                longx2 af[4], bf1[4], bf2[4];
                #pragma unroll
                for (int mi = 0; mi < 4; ++mi)
                    af[mi] = *(const longx2*)(As + (wm + mi * 16 + l16) * 128 + sw);
                #pragma unroll
                for (int ni = 0; ni < 4; ++ni) {
                    bf1[ni] = *(const longx2*)(Bs1 + (wn + ni * 16 + l16) * 128 + sw);
                    bf2[ni] = *(const longx2*)(Bs2 + (wn + ni * 16 + l16) * 128 + sw);
                }
                #pragma unroll
                for (int h = 0; h < 2; ++h)
                    #pragma unroll
                    for (int mi = 0; mi < 4; ++mi)
                        #pragma unroll
                        for (int ni = 0; ni < 4; ++ni) {
                            acc1[mi][ni] = __builtin_amdgcn_mfma_f32_16x16x32_fp8_fp8(
                                af[mi][h], bf1[ni][h], acc1[mi][ni], 0, 0, 0);
                            acc2[mi][ni] = __builtin_amdgcn_mfma_f32_16x16x32_fp8_fp8(
                                af[mi][h], bf2[ni][h], acc2[mi][ni], 0, 0, 0);
                        }
            }
        }
    }

    // ================= fused epilogue =================
    {
        const uchar_t* wl = Wl + tid * 80;
        unsigned int wq[4][4];
        #pragma unroll
        for (int mi = 0; mi < 4; ++mi)
            *(uint4*)&wq[mi][0] = *(const uint4*)(wl + mi * 16);

        float ifi[4][4], injn[4], injf[4];
        #pragma unroll
        for (int mi = 0; mi < 4; ++mi)
            #pragma unroll
            for (int r = 0; r < 4; ++r)
                ifi[mi][r] = incat[BDIM + i0 + wm + mi * 16 + quad * 4 + r];
        #pragma unroll
        for (int ni = 0; ni < 4; ++ni) {
            injn[ni] = incat[jm0 + wn + ni * 16 + l16];
            injf[ni] = incat[BDIM + jm0 + wn + ni * 16 + l16];
        }
        float rowsum[4][4];
        #pragma unroll
        for (int mi = 0; mi < 4; ++mi)
            #pragma unroll
            for (int r = 0; r < 4; ++r) rowsum[mi][r] = 0.f;
        #pragma unroll
        for (int mi = 0; mi < 4; ++mi)
            #pragma unroll
            for (int ni = 0; ni < 4; ++ni) {
                // unpack fp8 weights with CONSTANT byte selects (front-end requirement)
                float wv[4];
                wv[0] = __builtin_amdgcn_cvt_f32_fp8(wq[mi][ni], 0);
                wv[1] = __builtin_amdgcn_cvt_f32_fp8(wq[mi][ni], 1);
                wv[2] = __builtin_amdgcn_cvt_f32_fp8(wq[mi][ni], 2);
                wv[3] = __builtin_amdgcn_cvt_f32_fp8(wq[mi][ni], 3);
                #pragma unroll
                for (int r = 0; r < 4; ++r) {
                    int gi = i0 + wm + mi * 16 + quad * 4 + r;
                    int gc = jm0 + wn + ni * 16 + l16;
                    float e1 = __expf(acc1[mi][ni][r] * ifi[mi][r] * injn[ni]);
                    float e2 = __expf(acc2[mi][ni][r] * ifi[mi][r] * injf[ni]);
                    if (gc == gi) pos[gi] = e1;       // diag: pos; both self-pairs excluded
                    else rowsum[mi][r] += wv[r] * (e1 + e2);
                }
            }
        reduce_atomic(rowsum, neg, i0 + wm, quad, l16);
    }
}

// ---------------- finalize ----------------
__global__ __launch_bounds__(256) void finalize_kernel(const float* __restrict__ neg,
                                                       const float* __restrict__ pos,
                                                       float* __restrict__ out) {
    float s = 0.f;
    for (int i = threadIdx.x; i < BDIM; i += 256)
        s += logf(neg[i] + EPSF) - logf(pos[i]);
    #pragma unroll
    for (int off = 32; off > 0; off >>= 1) s += __shfl_down(s, off, 64);
    __shared__ float ws[4];
    int lane = threadIdx.x & 63, wid = threadIdx.x >> 6;
    if (lane == 0) ws[wid] = s;
    __syncthreads();
    if (threadIdx.x == 0) out[0] = (ws[0] + ws[1] + ws[2] + ws[3]) / (float)BDIM;
}

extern "C" void kernel_launch(void* const* d_in, const int* in_sizes, int n_in,
                              void* d_out, int out_size, void* d_ws, size_t ws_size,
                              hipStream_t stream) {
    const float* f     = (const float*)d_in[0];
    const float* noise = (const float*)d_in[1];
    const float* ref   = (const float*)d_in[2];
    float* out = (float*)d_out;

    char* w = (char*)d_ws;
    uchar_t* catb = (uchar_t*)w;                                 // 8 MB
    uchar_t* refb = (uchar_t*)(w + (size_t)8388608);             // 1 MB
    float* incat  = (float*)(w + (size_t)9437184);               // 8192 floats
    float* inr    = (float*)(w + (size_t)9469952);               // 4096 floats
    float* neg    = (float*)(w + (size_t)9486336);               // 4096 floats
    float* pos    = (float*)(w + (size_t)9502720);               // 4096 floats

    prep_kernel<<<3072, 256, 0, stream>>>(f, noise, ref, catb, refb, incat, inr, neg);

    dim3 grid(BDIM / 128, BDIM / 128);
    pair_mfma<<<grid, 256, 0, stream>>>(catb, refb, incat, inr, neg, pos);

    finalize_kernel<<<1, 256, 0, stream>>>(neg, pos, out);
}